// Round 1
// baseline (415.179 us; speedup 1.0000x reference)
//
#include <hip/hip_runtime.h>

#define LL 256   // sequence length
#define EE 64    // embed dim
#define HH 64    // hidden dim
#define GG 256   // 4*H gates
#define NSEQ 16  // sequences per block
#define ROWP 72  // padded LDS row stride in bf16 elems (144 B, 16B-aligned)

typedef __bf16 bf16_t;
typedef bf16_t bf16x8 __attribute__((ext_vector_type(8)));
typedef float  f32x4  __attribute__((ext_vector_type(4)));

union BfPack {
    unsigned short u[8];
    bf16x8 v;
};

__device__ __forceinline__ unsigned short f2bf(float f) {
    unsigned u = __float_as_uint(f);
    u = (u + 0x7FFFu + ((u >> 16) & 1u)) >> 16;   // RNE
    return (unsigned short)u;
}

#define LOG2E 1.44269504088896340736f

// v_exp_f32 + v_rcp_f32 based activations: no IEEE div_scale/div_fmas
// sequences (each sigm/tanh previously expanded to ~8-instr accurate division).
// v_rcp_f32 is ~1 ulp; error is far below the bf16 MFMA rounding upstream.
__device__ __forceinline__ float sigm(float x) {
    float e = __builtin_amdgcn_exp2f(-LOG2E * x);          // e^{-x}
    return __builtin_amdgcn_rcpf(1.0f + e);
}
__device__ __forceinline__ float tanh_fast(float x) {
    float t = fminf(fmaxf(x, -15.0f), 15.0f);
    float e = __builtin_amdgcn_exp2f((2.0f * LOG2E) * t);  // e^{2t}
    return 1.0f - 2.0f * __builtin_amdgcn_rcpf(e + 1.0f);
}

// lgkm-only barrier: the cross-wave dependency each timestep is LDS-only
// (h fragments + x commit). __syncthreads() would emit s_waitcnt vmcnt(0)
// before s_barrier, forcing the 4 scattered HBM out-stores (~600-900 cyc)
// to drain inside EVERY timestep's critical path with only 1 wave/SIMD to
// hide it. Stores have no reader -> they may retire asynchronously.
#define LGKM_BARRIER() asm volatile("s_waitcnt lgkmcnt(0)\n\ts_barrier" ::: "memory")

// One block = 16 sequences, one direction. 4 waves; wave w owns gate columns
// j = w*16 + (lane&15) within each 64-wide gate group, so i/f/g/o for a given
// (seq, j) land in the same lane/register. Weights live in registers as MFMA
// B-fragments; h recurs through LDS (bf16, A-fragment layout, double-
// buffered); c stays in registers. One (lgkm-only) barrier per timestep.
__global__ __launch_bounds__(256, 1)
void bilstm_mfma(const int* __restrict__ ids,
                 const float* __restrict__ embed,
                 const float* __restrict__ Wk_f, const float* __restrict__ Wr_f,
                 const float* __restrict__ b_f,
                 const float* __restrict__ Wk_b, const float* __restrict__ Wr_b,
                 const float* __restrict__ b_b,
                 float* __restrict__ out)
{
    const int dir = blockIdx.x >> 7;    // 0 fwd, 1 bwd
    const int grp = blockIdx.x & 127;
    const int n0  = grp * NSEQ;
    const int tid  = threadIdx.x;
    const int w    = tid >> 6;
    const int lane = tid & 63;
    const int l15  = lane & 15;
    const int quad = lane >> 4;
    const int j    = w * 16 + l15;      // gate sub-index in [0,64)

    const float* Wk = dir ? Wk_b : Wk_f;
    const float* Wr = dir ? Wr_b : Wr_f;
    const float* bv = dir ? b_b  : b_f;

    __shared__ __align__(16) short s_x[2][NSEQ][ROWP];  // 4.5 KB
    __shared__ __align__(16) short s_h[2][NSEQ][ROWP];  // 4.5 KB
    __shared__ int s_ids[NSEQ][LL];                     // 16 KB

    // stage ids (coalesced)
    for (int p = tid; p < NSEQ * LL; p += 256) {
        int m = p >> 8, t = p & 255;
        s_ids[m][t] = ids[(size_t)(n0 + m) * LL + t];
    }
    // zero both h buffers (h0 = 0)
    for (int p = tid; p < 2 * NSEQ * ROWP; p += 256)
        (&s_h[0][0][0])[p] = 0;

    __syncthreads();   // s_ids/s_h visible to all waves (full sync: once, cheap)

    // B fragments (bf16) + bias C-fragments, register-resident all kernel.
    // B-frag layout: lane holds B[k = kc*32 + quad*8 + e][n = l15], e=0..7.
    bf16x8 bfrag[4][4];   // [gate tt][k-chunk]
    f32x4  biasC[4];
    #pragma unroll
    for (int tt = 0; tt < 4; ++tt) {
        int g = tt * 64 + j;            // global gate column
        float bb = bv[g];
        biasC[tt] = (f32x4){bb, bb, bb, bb};
        #pragma unroll
        for (int kc = 0; kc < 4; ++kc) {
            BfPack pk;
            #pragma unroll
            for (int e = 0; e < 8; ++e) {
                int kg = kc * 32 + quad * 8 + e;
                float v = (kg < 64) ? Wk[(size_t)kg * GG + g]
                                    : Wr[(size_t)(kg - 64) * GG + g];
                pk.u[e] = f2bf(v);
            }
            bfrag[tt][kc] = pk.v;
        }
    }

    // gather x for the first step into buffer 0
    {
        int t0 = dir ? (LL - 1) : 0;
        #pragma unroll
        for (int u = 0; u < 2; ++u) {
            int pp = tid + u * 256;
            int m = pp >> 5, ep = pp & 31;
            int id = s_ids[m][t0];
            float2 xv = *(const float2*)&embed[(size_t)id * EE + 2 * ep];
            unsigned pk = (unsigned)f2bf(xv.x) | ((unsigned)f2bf(xv.y) << 16);
            *(unsigned*)&s_x[0][m][2 * ep] = pk;
        }
    }
    __syncthreads();

    float c[4] = {0.f, 0.f, 0.f, 0.f};   // cell state for rows m = quad*4+r
    const f32x4 zero4 = (f32x4){0.f, 0.f, 0.f, 0.f};

    for (int ts = 0; ts < LL; ++ts) {
        const int t  = dir ? (LL - 1 - ts) : ts;
        const int rb = ts & 1, wb = (ts + 1) & 1;

        // issue prefetch of x_{ts+1} early (embed table is L2/L3-resident)
        float2 px0, px1;
        const int pm0 = tid >> 5, pe = tid & 31, pm1 = pm0 + 8;
        const bool pf = (ts + 1 < LL);
        if (pf) {
            int tn = dir ? (LL - 2 - ts) : (ts + 1);
            px0 = *(const float2*)&embed[(size_t)s_ids[pm0][tn] * EE + 2 * pe];
            px1 = *(const float2*)&embed[(size_t)s_ids[pm1][tn] * EE + 2 * pe];
        }

        // A fragments: lane reads A[m = l15][k = quad*8 .. +7] (ds_read_b128)
        bf16x8 ax0 = *(const bf16x8*)&s_x[rb][l15][quad * 8];
        bf16x8 ax1 = *(const bf16x8*)&s_x[rb][l15][32 + quad * 8];
        bf16x8 ah0 = *(const bf16x8*)&s_h[rb][l15][quad * 8];
        bf16x8 ah1 = *(const bf16x8*)&s_h[rb][l15][32 + quad * 8];

        // z = (bias + x@Wk) + (h@Wr): two independent 2-deep MFMA chains per
        // gate instead of one 4-deep chain -- ax/ah are ready at the same time
        // post-barrier, so the critical path is 2 MFMA latencies, not 4.
        f32x4 acc[4];
        #pragma unroll
        for (int tt = 0; tt < 4; ++tt) {
            f32x4 axc = __builtin_amdgcn_mfma_f32_16x16x32_bf16(ax0, bfrag[tt][0], biasC[tt], 0, 0, 0);
            axc = __builtin_amdgcn_mfma_f32_16x16x32_bf16(ax1, bfrag[tt][1], axc, 0, 0, 0);
            f32x4 ahc = __builtin_amdgcn_mfma_f32_16x16x32_bf16(ah0, bfrag[tt][2], zero4, 0, 0, 0);
            ahc = __builtin_amdgcn_mfma_f32_16x16x32_bf16(ah1, bfrag[tt][3], ahc, 0, 0, 0);
            acc[tt] = axc + ahc;
        }

        // gate math in-register; C/D layout: row m = quad*4 + r, col = l15
        #pragma unroll
        for (int r = 0; r < 4; ++r) {
            float ig = sigm(acc[0][r]);
            float fg = sigm(acc[1][r]);
            float gg = tanh_fast(acc[2][r]);
            float og = sigm(acc[3][r]);
            c[r] = fg * c[r] + ig * gg;
            float hh = og * tanh_fast(c[r]);
            int m = quad * 4 + r;
            out[((size_t)(n0 + m) * LL + t) * (2 * HH) + dir * HH + j] = hh;
            s_h[wb][m][j] = (short)f2bf(hh);
        }

        // commit prefetched x into the write buffer
        if (pf) {
            unsigned pk0 = (unsigned)f2bf(px0.x) | ((unsigned)f2bf(px0.y) << 16);
            unsigned pk1 = (unsigned)f2bf(px1.x) | ((unsigned)f2bf(px1.y) << 16);
            *(unsigned*)&s_x[wb][pm0][2 * pe] = pk0;
            *(unsigned*)&s_x[wb][pm1][2 * pe] = pk1;
        }
        // orders LDS wb-buffer writes before next step's reads; does NOT
        // drain the global out-store queue (no reader -> async retire)
        LGKM_BARRIER();
    }
}

extern "C" void kernel_launch(void* const* d_in, const int* in_sizes, int n_in,
                              void* d_out, int out_size, void* d_ws, size_t ws_size,
                              hipStream_t stream) {
    const int*   ids   = (const int*)d_in[0];
    const float* embed = (const float*)d_in[1];
    const float* Wk_f  = (const float*)d_in[2];
    const float* Wr_f  = (const float*)d_in[3];
    const float* b_f   = (const float*)d_in[4];
    const float* Wk_b  = (const float*)d_in[5];
    const float* Wr_b  = (const float*)d_in[6];
    const float* b_b   = (const float*)d_in[7];
    float* out = (float*)d_out;

    dim3 grid(256);   // 128 seq-groups x 2 directions, 16 seqs each
    dim3 block(256);
    bilstm_mfma<<<grid, block, 0, stream>>>(ids, embed,
                                            Wk_f, Wr_f, b_f,
                                            Wk_b, Wr_b, b_b,
                                            out);
}